// Round 2
// baseline (1485.214 us; speedup 1.0000x reference)
//
#include <hip/hip_runtime.h>
#include <hip/hip_bf16.h>

typedef __bf16 bf16x8 __attribute__((ext_vector_type(8)));
typedef float  f32x4  __attribute__((ext_vector_type(4)));

#define NB 4
#define SEQ 4096
#define DIM 128

// ---------------------------------------------------------------------------
// Kernel 1: QKV projection in fp32 (accuracy), outputs bf16.
//   Q[row][e] = (x[row]·Wq[e] + bq[e]) * 1/sqrt(128)   (scale folded into Q)
//   K[row][e] =  x[row]·Wk[e] + bk[e]
//   Vt[b][e][s] = x[row]·Wv[e] + bv[e]                 (V stored transposed)
// grid (256 row-tiles of 64, 3), block 256.
// ---------------------------------------------------------------------------
__global__ __launch_bounds__(256) void qkv_proj(
    const float* __restrict__ x,
    const float* __restrict__ Wq, const float* __restrict__ bq,
    const float* __restrict__ Wk, const float* __restrict__ bk,
    const float* __restrict__ Wv, const float* __restrict__ bv,
    __bf16* __restrict__ Q, __bf16* __restrict__ K, __bf16* __restrict__ Vt)
{
    __shared__ float xs[64][128];
    const int t  = threadIdx.x;
    const int rt = blockIdx.x;      // row tile (64 rows)
    const int which = blockIdx.y;   // 0=q 1=k 2=v

    const float* W; const float* bias;
    if (which == 0)      { W = Wq; bias = bq; }
    else if (which == 1) { W = Wk; bias = bk; }
    else                 { W = Wv; bias = bv; }

    // stage x tile: 64x128 fp32 = 2048 float4
    const float4* xsrc = (const float4*)(x + rt * 64 * 128);
    float4* xdst = (float4*)&xs[0][0];
    #pragma unroll
    for (int ii = 0; ii < 8; ++ii) xdst[t + ii * 256] = xsrc[t + ii * 256];
    __syncthreads();

    const int eg = t & 31;   // 32 e-groups of 4 channels
    const int rg = t >> 5;   // 8 row-groups of 8 rows

    float acc[4][8];
    #pragma unroll
    for (int ee = 0; ee < 4; ++ee) {
        float bv0 = bias[eg * 4 + ee];
        #pragma unroll
        for (int i = 0; i < 8; ++i) acc[ee][i] = bv0;
    }

    #pragma unroll
    for (int dc = 0; dc < 8; ++dc) {              // 16-d chunks
        float4 wv[4][4];
        #pragma unroll
        for (int ee = 0; ee < 4; ++ee) {
            const float4* wp = (const float4*)(W + (eg * 4 + ee) * 128 + dc * 16);
            #pragma unroll
            for (int jj = 0; jj < 4; ++jj) wv[ee][jj] = wp[jj];
        }
        #pragma unroll
        for (int i = 0; i < 8; ++i) {
            #pragma unroll
            for (int jj = 0; jj < 4; ++jj) {
                float4 x4 = *(const float4*)&xs[rg * 8 + i][dc * 16 + jj * 4];
                #pragma unroll
                for (int ee = 0; ee < 4; ++ee) {
                    acc[ee][i] += x4.x * wv[ee][jj].x + x4.y * wv[ee][jj].y
                                + x4.z * wv[ee][jj].z + x4.w * wv[ee][jj].w;
                }
            }
        }
    }

    const float qscale = 0.08838834764831845f;  // 1/sqrt(128)
    #pragma unroll
    for (int ee = 0; ee < 4; ++ee) {
        int e = eg * 4 + ee;
        #pragma unroll
        for (int i = 0; i < 8; ++i) {
            int row = rt * 64 + rg * 8 + i;
            float v = acc[ee][i];
            if (which == 0) {
                Q[row * 128 + e] = (__bf16)(v * qscale);
            } else if (which == 1) {
                K[row * 128 + e] = (__bf16)v;
            } else {
                int b = row >> 12, s = row & 4095;
                Vt[b * (128 * 4096) + e * 4096 + s] = (__bf16)v;
            }
        }
    }
}

// ---------------------------------------------------------------------------
// Kernel 2: flash attention fwd, bf16 MFMA 16x16x32, fp32 online softmax.
// 256 blocks (one per 64-row Q tile), 4 waves x 16 q-rows.
// KV tiles of 64 keys staged in LDS (single-buffered).
// MFMA layouts (gfx950 16x16x32):
//   A: row=l&15,  k=(l>>4)*8+j   (8 contiguous k per lane -> 16B loads)
//   B: col=l&15,  k=(l>>4)*8+j
//   C/D: col=l&15, row=(l>>4)*4+reg   [verified m89]
// ---------------------------------------------------------------------------
__global__ __launch_bounds__(256) void attn_fwd(
    const __bf16* __restrict__ Qg,
    const __bf16* __restrict__ Kg,
    const __bf16* __restrict__ Vt,
    float* __restrict__ out)
{
    __shared__ __bf16 Kl[64][136];    // K tile, row=key, +8 pad
    __shared__ __bf16 Vl[128][72];    // V^T tile, row=d, +8 pad
    __shared__ __bf16 Pl[4][16][72];  // per-wave P transpose buffer

    const int t  = threadIdx.x;
    const int w  = t >> 6;
    const int l  = t & 63;
    const int lg = l >> 4;      // lane group 0..3
    const int ll = l & 15;

    const int bid = blockIdx.x;
    const int b   = bid >> 6;
    const int qt  = bid & 63;
    const int qrow0 = qt * 64 + w * 16;   // within batch

    // Q A-fragments (scale already folded in)
    bf16x8 qa[4];
    const __bf16* qbase = Qg + (b * 4096 + qrow0 + ll) * 128 + lg * 8;
    #pragma unroll
    for (int kb = 0; kb < 4; ++kb) qa[kb] = *(const bf16x8*)(qbase + kb * 32);

    f32x4 o[8];
    #pragma unroll
    for (int dt = 0; dt < 8; ++dt) o[dt] = (f32x4){0.f, 0.f, 0.f, 0.f};
    float m[4], lsum[4];
    #pragma unroll
    for (int r = 0; r < 4; ++r) { m[r] = -1e30f; lsum[r] = 0.f; }

    const __bf16* kbase = Kg + b * 4096 * 128;
    const __bf16* vbase = Vt + b * 128 * 4096;

    for (int kv0 = 0; kv0 < SEQ; kv0 += 64) {
        __syncthreads();
        // stage K tile: 64 rows x 128 cols = 1024 bf16x8 units (16 units/row)
        #pragma unroll
        for (int ii = 0; ii < 4; ++ii) {
            int u = t + ii * 256;
            int r = u >> 4, c = u & 15;
            bf16x8 val = *(const bf16x8*)(kbase + (kv0 + r) * 128 + c * 8);
            *(bf16x8*)&Kl[r][c * 8] = val;
        }
        // stage V^T tile: 128 d-rows x 64 keys = 1024 bf16x8 units (8 units/row)
        #pragma unroll
        for (int ii = 0; ii < 4; ++ii) {
            int u = t + ii * 256;
            int dr = u >> 3, c = u & 7;
            bf16x8 val = *(const bf16x8*)(vbase + dr * 4096 + kv0 + c * 8);
            *(bf16x8*)&Vl[dr][c * 8] = val;
        }
        __syncthreads();

        // QK^T: 16 MFMAs -> scores 16x64 in C layout
        float sc[4][4];
        #pragma unroll
        for (int nt = 0; nt < 4; ++nt) {
            f32x4 f = (f32x4){0.f, 0.f, 0.f, 0.f};
            #pragma unroll
            for (int kb = 0; kb < 4; ++kb) {
                bf16x8 kf = *(const bf16x8*)&Kl[nt * 16 + ll][kb * 32 + lg * 8];
                f = __builtin_amdgcn_mfma_f32_16x16x32_bf16(qa[kb], kf, f, 0, 0, 0);
            }
            #pragma unroll
            for (int r = 0; r < 4; ++r) sc[nt][r] = f[r];
        }

        // online softmax (fp32). row r of this lane = (l>>4)*4 + r.
        float mnew[4], alpha[4], rsum[4];
        #pragma unroll
        for (int r = 0; r < 4; ++r) {
            float mx = fmaxf(fmaxf(sc[0][r], sc[1][r]), fmaxf(sc[2][r], sc[3][r]));
            #pragma unroll
            for (int sh = 1; sh < 16; sh <<= 1)
                mx = fmaxf(mx, __shfl_xor(mx, sh, 64));
            mnew[r] = fmaxf(m[r], mx);
            alpha[r] = __expf(m[r] - mnew[r]);
            rsum[r] = 0.f;
        }
        __bf16 pb[4][4];
        #pragma unroll
        for (int nt = 0; nt < 4; ++nt) {
            #pragma unroll
            for (int r = 0; r < 4; ++r) {
                float p = __expf(sc[nt][r] - mnew[r]);
                __bf16 pv = (__bf16)p;
                pb[nt][r] = pv;
                rsum[r] += (float)pv;   // sum bf16-rounded P: normalization cancels rounding
            }
        }
        #pragma unroll
        for (int r = 0; r < 4; ++r) {
            #pragma unroll
            for (int sh = 1; sh < 16; sh <<= 1)
                rsum[r] += __shfl_xor(rsum[r], sh, 64);
            lsum[r] = lsum[r] * alpha[r] + rsum[r];
            m[r] = mnew[r];
        }
        // rescale O
        #pragma unroll
        for (int dt = 0; dt < 8; ++dt)
            #pragma unroll
            for (int r = 0; r < 4; ++r) o[dt][r] *= alpha[r];

        // P -> LDS (C layout -> A layout transpose), per-wave buffer
        #pragma unroll
        for (int nt = 0; nt < 4; ++nt)
            #pragma unroll
            for (int r = 0; r < 4; ++r)
                Pl[w][lg * 4 + r][nt * 16 + ll] = pb[nt][r];
        asm volatile("s_waitcnt lgkmcnt(0)" ::: "memory");  // intra-wave LDS visibility

        // PV: O += P @ V  (16 MFMAs)
        #pragma unroll
        for (int kc = 0; kc < 2; ++kc) {
            bf16x8 pa = *(const bf16x8*)&Pl[w][ll][kc * 32 + lg * 8];
            #pragma unroll
            for (int dt = 0; dt < 8; ++dt) {
                bf16x8 vb = *(const bf16x8*)&Vl[dt * 16 + ll][kc * 32 + lg * 8];
                o[dt] = __builtin_amdgcn_mfma_f32_16x16x32_bf16(pa, vb, o[dt], 0, 0, 0);
            }
        }
    }

    // epilogue: normalize + store fp32
    float* ob = out + (long)(b * 4096 + qrow0) * 128;
    #pragma unroll
    for (int r = 0; r < 4; ++r) {
        float inv = 1.f / lsum[r];
        int qr = lg * 4 + r;
        #pragma unroll
        for (int dt = 0; dt < 8; ++dt)
            ob[qr * 128 + dt * 16 + ll] = o[dt][r] * inv;
    }
}

extern "C" void kernel_launch(void* const* d_in, const int* in_sizes, int n_in,
                              void* d_out, int out_size, void* d_ws, size_t ws_size,
                              hipStream_t stream) {
    (void)in_sizes; (void)n_in; (void)out_size; (void)ws_size;
    const float* x  = (const float*)d_in[0];
    const float* Wq = (const float*)d_in[1];
    const float* bq = (const float*)d_in[2];
    const float* Wk = (const float*)d_in[3];
    const float* bk = (const float*)d_in[4];
    const float* Wv = (const float*)d_in[5];
    const float* bv = (const float*)d_in[6];
    float* out = (float*)d_out;

    __bf16* Q  = (__bf16*)d_ws;                  // 4 MB
    __bf16* K  = Q + NB * SEQ * DIM;             // 4 MB
    __bf16* Vt = K + NB * SEQ * DIM;             // 4 MB

    dim3 g1(256, 3), b1(256);
    qkv_proj<<<g1, b1, 0, stream>>>(x, Wq, bq, Wk, bk, Wv, bv, Q, K, Vt);
    attn_fwd<<<256, 256, 0, stream>>>(Q, K, Vt, out);
}

// Round 3
// 198.636 us; speedup vs baseline: 7.4771x; 7.4771x over previous
//
#include <hip/hip_runtime.h>
#include <hip/hip_bf16.h>

typedef __bf16 bf16x8 __attribute__((ext_vector_type(8)));
typedef float  f32x4  __attribute__((ext_vector_type(4)));

#define NB 4
#define SEQ 4096
#define DIM 128

// ---------------------------------------------------------------------------
// Kernel 1: QKV projection in fp32 (accuracy), outputs bf16.
//   Q[row][e] = (x[row]·Wq[e] + bq[e]) * 1/sqrt(128)   (scale folded into Q)
//   K[row][e] =  x[row]·Wk[e] + bk[e]
//   Vt[b][e][s] = x[row]·Wv[e] + bv[e]                 (V stored transposed)
// grid (256 row-tiles of 64, 3), block 256.
// R2 fix: dc loop NOT unrolled; W loaded in 16-VGPR chunks -> no spill.
// ---------------------------------------------------------------------------
__global__ __launch_bounds__(256) void qkv_proj(
    const float* __restrict__ x,
    const float* __restrict__ Wq, const float* __restrict__ bq,
    const float* __restrict__ Wk, const float* __restrict__ bk,
    const float* __restrict__ Wv, const float* __restrict__ bv,
    __bf16* __restrict__ Q, __bf16* __restrict__ K, __bf16* __restrict__ Vt)
{
    __shared__ float xs[64][128];
    const int t  = threadIdx.x;
    const int rt = blockIdx.x;      // row tile (64 rows)
    const int which = blockIdx.y;   // 0=q 1=k 2=v

    const float* W; const float* bias;
    if (which == 0)      { W = Wq; bias = bq; }
    else if (which == 1) { W = Wk; bias = bk; }
    else                 { W = Wv; bias = bv; }

    // stage x tile: 64x128 fp32 = 2048 float4
    const float4* xsrc = (const float4*)(x + rt * 64 * 128);
    float4* xdst = (float4*)&xs[0][0];
    #pragma unroll
    for (int ii = 0; ii < 8; ++ii) xdst[t + ii * 256] = xsrc[t + ii * 256];
    __syncthreads();

    const int eg = t & 31;   // 32 e-groups of 4 channels
    const int rg = t >> 5;   // 8 row-groups of 8 rows

    float acc[4][8];
    #pragma unroll
    for (int ee = 0; ee < 4; ++ee) {
        float b0 = bias[eg * 4 + ee];
        #pragma unroll
        for (int i = 0; i < 8; ++i) acc[ee][i] = b0;
    }

    #pragma unroll 1
    for (int dc = 0; dc < 8; ++dc) {              // 16-d chunks, NOT unrolled
        #pragma unroll
        for (int jj = 0; jj < 4; ++jj) {
            float4 wv4[4];
            #pragma unroll
            for (int ee = 0; ee < 4; ++ee)
                wv4[ee] = *(const float4*)(W + (eg * 4 + ee) * 128 + dc * 16 + jj * 4);
            #pragma unroll
            for (int i = 0; i < 8; ++i) {
                float4 x4 = *(const float4*)&xs[rg * 8 + i][dc * 16 + jj * 4];
                #pragma unroll
                for (int ee = 0; ee < 4; ++ee) {
                    acc[ee][i] += x4.x * wv4[ee].x + x4.y * wv4[ee].y
                                + x4.z * wv4[ee].z + x4.w * wv4[ee].w;
                }
            }
        }
    }

    const float qscale = 0.08838834764831845f;  // 1/sqrt(128)
    #pragma unroll
    for (int ee = 0; ee < 4; ++ee) {
        int e = eg * 4 + ee;
        #pragma unroll
        for (int i = 0; i < 8; ++i) {
            int row = rt * 64 + rg * 8 + i;
            float v = acc[ee][i];
            if (which == 0) {
                Q[row * 128 + e] = (__bf16)(v * qscale);
            } else if (which == 1) {
                K[row * 128 + e] = (__bf16)v;
            } else {
                int b = row >> 12, s = row & 4095;
                Vt[b * (128 * 4096) + e * 4096 + s] = (__bf16)v;
            }
        }
    }
}

// ---------------------------------------------------------------------------
// Kernel 2: flash attention fwd, bf16 MFMA 16x16x32, fp32 online softmax.
// (unchanged from R1 — verified correct; optimize next round with counters)
// ---------------------------------------------------------------------------
__global__ __launch_bounds__(256) void attn_fwd(
    const __bf16* __restrict__ Qg,
    const __bf16* __restrict__ Kg,
    const __bf16* __restrict__ Vt,
    float* __restrict__ out)
{
    __shared__ __bf16 Kl[64][136];    // K tile, row=key, +8 pad
    __shared__ __bf16 Vl[128][72];    // V^T tile, row=d, +8 pad
    __shared__ __bf16 Pl[4][16][72];  // per-wave P transpose buffer

    const int t  = threadIdx.x;
    const int w  = t >> 6;
    const int l  = t & 63;
    const int lg = l >> 4;      // lane group 0..3
    const int ll = l & 15;

    const int bid = blockIdx.x;
    const int b   = bid >> 6;
    const int qt  = bid & 63;
    const int qrow0 = qt * 64 + w * 16;   // within batch

    // Q A-fragments (scale already folded in)
    bf16x8 qa[4];
    const __bf16* qbase = Qg + (b * 4096 + qrow0 + ll) * 128 + lg * 8;
    #pragma unroll
    for (int kb = 0; kb < 4; ++kb) qa[kb] = *(const bf16x8*)(qbase + kb * 32);

    f32x4 o[8];
    #pragma unroll
    for (int dt = 0; dt < 8; ++dt) o[dt] = (f32x4){0.f, 0.f, 0.f, 0.f};
    float m[4], lsum[4];
    #pragma unroll
    for (int r = 0; r < 4; ++r) { m[r] = -1e30f; lsum[r] = 0.f; }

    const __bf16* kbase = Kg + b * 4096 * 128;
    const __bf16* vbase = Vt + b * 128 * 4096;

    for (int kv0 = 0; kv0 < SEQ; kv0 += 64) {
        __syncthreads();
        // stage K tile: 64 rows x 128 cols = 1024 bf16x8 units (16 units/row)
        #pragma unroll
        for (int ii = 0; ii < 4; ++ii) {
            int u = t + ii * 256;
            int r = u >> 4, c = u & 15;
            bf16x8 val = *(const bf16x8*)(kbase + (kv0 + r) * 128 + c * 8);
            *(bf16x8*)&Kl[r][c * 8] = val;
        }
        // stage V^T tile: 128 d-rows x 64 keys = 1024 bf16x8 units (8 units/row)
        #pragma unroll
        for (int ii = 0; ii < 4; ++ii) {
            int u = t + ii * 256;
            int dr = u >> 3, c = u & 7;
            bf16x8 val = *(const bf16x8*)(vbase + dr * 4096 + kv0 + c * 8);
            *(bf16x8*)&Vl[dr][c * 8] = val;
        }
        __syncthreads();

        // QK^T: 16 MFMAs -> scores 16x64 in C layout
        float sc[4][4];
        #pragma unroll
        for (int nt = 0; nt < 4; ++nt) {
            f32x4 f = (f32x4){0.f, 0.f, 0.f, 0.f};
            #pragma unroll
            for (int kb = 0; kb < 4; ++kb) {
                bf16x8 kf = *(const bf16x8*)&Kl[nt * 16 + ll][kb * 32 + lg * 8];
                f = __builtin_amdgcn_mfma_f32_16x16x32_bf16(qa[kb], kf, f, 0, 0, 0);
            }
            #pragma unroll
            for (int r = 0; r < 4; ++r) sc[nt][r] = f[r];
        }

        // online softmax (fp32). row r of this lane = (l>>4)*4 + r.
        float mnew[4], alpha[4], rsum[4];
        #pragma unroll
        for (int r = 0; r < 4; ++r) {
            float mx = fmaxf(fmaxf(sc[0][r], sc[1][r]), fmaxf(sc[2][r], sc[3][r]));
            #pragma unroll
            for (int sh = 1; sh < 16; sh <<= 1)
                mx = fmaxf(mx, __shfl_xor(mx, sh, 64));
            mnew[r] = fmaxf(m[r], mx);
            alpha[r] = __expf(m[r] - mnew[r]);
            rsum[r] = 0.f;
        }
        __bf16 pb[4][4];
        #pragma unroll
        for (int nt = 0; nt < 4; ++nt) {
            #pragma unroll
            for (int r = 0; r < 4; ++r) {
                float p = __expf(sc[nt][r] - mnew[r]);
                __bf16 pv = (__bf16)p;
                pb[nt][r] = pv;
                rsum[r] += (float)pv;   // sum bf16-rounded P: normalization cancels rounding
            }
        }
        #pragma unroll
        for (int r = 0; r < 4; ++r) {
            #pragma unroll
            for (int sh = 1; sh < 16; sh <<= 1)
                rsum[r] += __shfl_xor(rsum[r], sh, 64);
            lsum[r] = lsum[r] * alpha[r] + rsum[r];
            m[r] = mnew[r];
        }
        // rescale O
        #pragma unroll
        for (int dt = 0; dt < 8; ++dt)
            #pragma unroll
            for (int r = 0; r < 4; ++r) o[dt][r] *= alpha[r];

        // P -> LDS (C layout -> A layout transpose), per-wave buffer
        #pragma unroll
        for (int nt = 0; nt < 4; ++nt)
            #pragma unroll
            for (int r = 0; r < 4; ++r)
                Pl[w][lg * 4 + r][nt * 16 + ll] = pb[nt][r];
        asm volatile("s_waitcnt lgkmcnt(0)" ::: "memory");  // intra-wave LDS visibility

        // PV: O += P @ V  (16 MFMAs)
        #pragma unroll
        for (int kc = 0; kc < 2; ++kc) {
            bf16x8 pa = *(const bf16x8*)&Pl[w][ll][kc * 32 + lg * 8];
            #pragma unroll
            for (int dt = 0; dt < 8; ++dt) {
                bf16x8 vb = *(const bf16x8*)&Vl[dt * 16 + ll][kc * 32 + lg * 8];
                o[dt] = __builtin_amdgcn_mfma_f32_16x16x32_bf16(pa, vb, o[dt], 0, 0, 0);
            }
        }
    }

    // epilogue: normalize + store fp32
    float* ob = out + (long)(b * 4096 + qrow0) * 128;
    #pragma unroll
    for (int r = 0; r < 4; ++r) {
        float inv = 1.f / lsum[r];
        int qr = lg * 4 + r;
        #pragma unroll
        for (int dt = 0; dt < 8; ++dt)
            ob[qr * 128 + dt * 16 + ll] = o[dt][r] * inv;
    }
}

extern "C" void kernel_launch(void* const* d_in, const int* in_sizes, int n_in,
                              void* d_out, int out_size, void* d_ws, size_t ws_size,
                              hipStream_t stream) {
    (void)in_sizes; (void)n_in; (void)out_size; (void)ws_size;
    const float* x  = (const float*)d_in[0];
    const float* Wq = (const float*)d_in[1];
    const float* bq = (const float*)d_in[2];
    const float* Wk = (const float*)d_in[3];
    const float* bk = (const float*)d_in[4];
    const float* Wv = (const float*)d_in[5];
    const float* bv = (const float*)d_in[6];
    float* out = (float*)d_out;

    __bf16* Q  = (__bf16*)d_ws;                  // 4 MB
    __bf16* K  = Q + NB * SEQ * DIM;             // 4 MB
    __bf16* Vt = K + NB * SEQ * DIM;             // 4 MB

    dim3 g1(256, 3), b1(256);
    qkv_proj<<<g1, b1, 0, stream>>>(x, Wq, bq, Wk, bk, Wv, bv, Q, K, Vt);
    attn_fwd<<<256, 256, 0, stream>>>(Q, K, Vt, out);
}

// Round 5
// 109.077 us; speedup vs baseline: 13.6162x; 1.8211x over previous
//
#include <hip/hip_runtime.h>
#include <hip/hip_bf16.h>

typedef __bf16 bf16x8 __attribute__((ext_vector_type(8)));
typedef __bf16 bf16x4 __attribute__((ext_vector_type(4)));
typedef float  f32x4  __attribute__((ext_vector_type(4)));

#define NB 4
#define SEQ 4096
#define DIM 128

static __device__ __forceinline__ unsigned int bf16bits(__bf16 h) {
    return (unsigned int)__builtin_bit_cast(unsigned short, h);
}

// ---------------------------------------------------------------------------
// Kernel 0: W fp32 -> (Wh, Wl) bf16 split pair.  Wh = bf16(w), Wl = bf16(w-Wh)
// grid 48 x 256 over 3*4096 float4.
// ---------------------------------------------------------------------------
__global__ __launch_bounds__(256) void wconv(
    const float* __restrict__ Wq, const float* __restrict__ Wk,
    const float* __restrict__ Wv,
    __bf16* __restrict__ Wh, __bf16* __restrict__ Wl)
{
    int idx = blockIdx.x * 256 + threadIdx.x;     // float4 index, 12288 total
    int which = idx >> 12;                        // 4096 float4 per matrix
    int off = (idx & 4095) * 4;
    const float* W = which == 0 ? Wq : (which == 1 ? Wk : Wv);
    float4 v = *(const float4*)(W + off);
    bf16x4 h, lo;
    h[0] = (__bf16)v.x; h[1] = (__bf16)v.y; h[2] = (__bf16)v.z; h[3] = (__bf16)v.w;
    lo[0] = (__bf16)(v.x - (float)h[0]);
    lo[1] = (__bf16)(v.y - (float)h[1]);
    lo[2] = (__bf16)(v.z - (float)h[2]);
    lo[3] = (__bf16)(v.w - (float)h[3]);
    *(bf16x4*)(Wh + which * 16384 + off) = h;
    *(bf16x4*)(Wl + which * 16384 + off) = lo;
}

// ---------------------------------------------------------------------------
// Kernel 1: QKV projection via 3-term split-bf16 MFMA (fp32-grade accuracy):
//   y = xh@Wh + xh@Wl + xl@Wh   (xl*Wl term ~2^-18, dropped)
// grid (256 row-tiles of 64, 3 which), block 256 (4 waves x 16 rows).
// Epilogue goes through LDS for coalesced stores; V stored transposed.
// ---------------------------------------------------------------------------
__global__ __launch_bounds__(256) void qkv_proj(
    const float* __restrict__ x,
    const __bf16* __restrict__ Whg, const __bf16* __restrict__ Wlg,
    const float* __restrict__ bq, const float* __restrict__ bk,
    const float* __restrict__ bv,
    __bf16* __restrict__ Q, __bf16* __restrict__ K, __bf16* __restrict__ Vt)
{
    __shared__ __bf16 vbuf[64][136];
    const int t  = threadIdx.x;
    const int w  = t >> 6, l = t & 63, lg = l >> 4, ll = l & 15;
    const int rt = blockIdx.x, which = blockIdx.y;

    const __bf16* Wh = Whg + which * 16384;
    const __bf16* Wl = Wlg + which * 16384;
    const float* bias = which == 0 ? bq : (which == 1 ? bk : bv);

    float bfr[8];
    #pragma unroll
    for (int ct = 0; ct < 8; ++ct) bfr[ct] = bias[ct * 16 + ll];

    f32x4 acc[8];
    #pragma unroll
    for (int ct = 0; ct < 8; ++ct) acc[ct] = (f32x4){0.f, 0.f, 0.f, 0.f};

    const float* xrow = x + (rt * 64 + w * 16 + ll) * 128;

    #pragma unroll 1
    for (int kb = 0; kb < 4; ++kb) {
        float4 xa = *(const float4*)(xrow + kb * 32 + lg * 8);
        float4 xb = *(const float4*)(xrow + kb * 32 + lg * 8 + 4);
        float xv[8] = {xa.x, xa.y, xa.z, xa.w, xb.x, xb.y, xb.z, xb.w};
        bf16x8 xh, xl;
        #pragma unroll
        for (int j = 0; j < 8; ++j) {
            __bf16 h = (__bf16)xv[j];
            xh[j] = h;
            xl[j] = (__bf16)(xv[j] - (float)h);
        }
        #pragma unroll
        for (int ct = 0; ct < 8; ++ct) {
            bf16x8 wh = *(const bf16x8*)(Wh + (ct * 16 + ll) * 128 + kb * 32 + lg * 8);
            bf16x8 wl = *(const bf16x8*)(Wl + (ct * 16 + ll) * 128 + kb * 32 + lg * 8);
            acc[ct] = __builtin_amdgcn_mfma_f32_16x16x32_bf16(xh, wh, acc[ct], 0, 0, 0);
            acc[ct] = __builtin_amdgcn_mfma_f32_16x16x32_bf16(xh, wl, acc[ct], 0, 0, 0);
            acc[ct] = __builtin_amdgcn_mfma_f32_16x16x32_bf16(xl, wh, acc[ct], 0, 0, 0);
        }
    }

    const float qscale = 0.08838834764831845f;  // 1/sqrt(128)
    const float scale = (which == 0) ? qscale : 1.0f;
    #pragma unroll
    for (int ct = 0; ct < 8; ++ct)
        #pragma unroll
        for (int r = 0; r < 4; ++r)
            vbuf[w * 16 + lg * 4 + r][ct * 16 + ll] = (__bf16)((acc[ct][r] + bfr[ct]) * scale);
    __syncthreads();

    if (which < 2) {
        // row-major coalesced: thread t -> row t>>2, 32-col chunk (t&3)
        __bf16* dst = (which == 0 ? Q : K) + (rt * 64 + (t >> 2)) * 128 + (t & 3) * 32;
        const __bf16* src = &vbuf[t >> 2][(t & 3) * 32];
        #pragma unroll
        for (int i = 0; i < 4; ++i) ((bf16x8*)dst)[i] = ((const bf16x8*)src)[i];
    } else {
        // transposed: thread t -> channel e = t>>1, 32-seq chunk (t&1)
        int e = t >> 1, sh = (t & 1) * 32;
        int bb = rt >> 6, sb = (rt & 63) * 64 + sh;
        __bf16 tmp[32];
        #pragma unroll
        for (int j = 0; j < 32; ++j) tmp[j] = vbuf[sh + j][e];
        __bf16* dst = Vt + bb * (128 * 4096) + e * 4096 + sb;
        #pragma unroll
        for (int i = 0; i < 4; ++i) ((bf16x8*)dst)[i] = *(const bf16x8*)&tmp[i * 8];
    }
}

// ---------------------------------------------------------------------------
// Kernel 2: flash attention, split-K over keys, swapped QK^T, async staging.
// 256 blocks x 512 threads (8 waves = 2 groups x 4 waves; 2 waves/SIMD).
// Group g handles keys [g*2048, (g+1)*2048); merge at end via LDS.
// Swapped QK^T: f = mfma(K, Q) -> lane (ll,lg) reg(nt,r) = S[key=nt*16+lg*4+r][q=ll]
//   -> softmax state (m,lsum) is a per-lane SCALAR for q-row ll.
// P repack: lane packs p[nt][0..3] as 2 dwords -> PlT[w][qrow=ll][key], padded 72.
// PV (normal orientation): A=PlT rows, B=Vl cols; C/D row=(l>>4)*4+r, col=l&15.
// ---------------------------------------------------------------------------
__global__ __launch_bounds__(512, 2) void attn_fwd(
    const __bf16* __restrict__ Qg,
    const __bf16* __restrict__ Kg,
    const __bf16* __restrict__ Vt,
    float* __restrict__ out)
{
    __shared__ __bf16 Kl[2][64][136];
    __shared__ __bf16 Vl[2][128][72];
    __shared__ __bf16 PlT[8][16][72];
    __shared__ float  Obuf[64][132];
    __shared__ float  m_l[2][64], l_l[2][64];

    const int t  = threadIdx.x;
    const int w  = t >> 6;        // 0..7
    const int g  = w >> 2;        // split-K group
    const int wl = w & 3;         // row-frag within group
    const int l  = t & 63, lg = l >> 4, ll = l & 15;
    const int tg = t & 255;       // thread within group

    const int bid = blockIdx.x;
    const int b = bid >> 6, qt = bid & 63;
    const int rb = wl * 16;
    const int qrow0 = qt * 64 + rb;

    bf16x8 qa[4];
    const __bf16* qbase = Qg + (b * 4096 + qrow0 + ll) * 128 + lg * 8;
    #pragma unroll
    for (int kb = 0; kb < 4; ++kb) qa[kb] = *(const bf16x8*)(qbase + kb * 32);

    f32x4 o[8];
    #pragma unroll
    for (int dt = 0; dt < 8; ++dt) o[dt] = (f32x4){0.f, 0.f, 0.f, 0.f};
    float m = -1e30f, lsum = 0.f;

    const __bf16* kbase = Kg + (long)(b * 4096 + g * 2048) * 128;
    const __bf16* vbase = Vt + (long)b * 128 * 4096 + g * 2048;

    const int ur[4] = {tg >> 4, (tg + 256) >> 4, (tg + 512) >> 4, (tg + 768) >> 4};
    const int uc[4] = {tg & 15, tg & 15, tg & 15, tg & 15};
    const int vr[4] = {tg >> 3, (tg + 256) >> 3, (tg + 512) >> 3, (tg + 768) >> 3};
    const int vc = tg & 7;

    bf16x8 kreg[4], vreg[4];
    // prologue: stage tile 0
    #pragma unroll
    for (int ii = 0; ii < 4; ++ii)
        kreg[ii] = *(const bf16x8*)(kbase + ur[ii] * 128 + uc[ii] * 8);
    #pragma unroll
    for (int ii = 0; ii < 4; ++ii)
        vreg[ii] = *(const bf16x8*)(vbase + vr[ii] * 4096 + vc * 8);
    #pragma unroll
    for (int ii = 0; ii < 4; ++ii) *(bf16x8*)&Kl[g][ur[ii]][uc[ii] * 8] = kreg[ii];
    #pragma unroll
    for (int ii = 0; ii < 4; ++ii) *(bf16x8*)&Vl[g][vr[ii]][vc * 8] = vreg[ii];
    __syncthreads();

    for (int it = 0; it < 32; ++it) {
        // issue next-tile global loads early (hide under compute)
        if (it + 1 < 32) {
            int kv = (it + 1) * 64;
            #pragma unroll
            for (int ii = 0; ii < 4; ++ii)
                kreg[ii] = *(const bf16x8*)(kbase + (kv + ur[ii]) * 128 + uc[ii] * 8);
            #pragma unroll
            for (int ii = 0; ii < 4; ++ii)
                vreg[ii] = *(const bf16x8*)(vbase + vr[ii] * 4096 + kv + vc * 8);
        }

        // QK^T swapped: p[nt][r] = S[key = nt*16+lg*4+r][qrow = ll]
        float p[4][4];
        #pragma unroll
        for (int nt = 0; nt < 4; ++nt) {
            f32x4 f = (f32x4){0.f, 0.f, 0.f, 0.f};
            #pragma unroll
            for (int kb = 0; kb < 4; ++kb) {
                bf16x8 kf = *(const bf16x8*)&Kl[g][nt * 16 + ll][kb * 32 + lg * 8];
                f = __builtin_amdgcn_mfma_f32_16x16x32_bf16(kf, qa[kb], f, 0, 0, 0);
            }
            #pragma unroll
            for (int r = 0; r < 4; ++r) p[nt][r] = f[r];
        }

        // row stats for q-row ll (lanes ll, ll+16, ll+32, ll+48 share)
        float mx = p[0][0];
        #pragma unroll
        for (int nt = 0; nt < 4; ++nt)
            #pragma unroll
            for (int r = 0; r < 4; ++r) mx = fmaxf(mx, p[nt][r]);
        mx = fmaxf(mx, __shfl_xor(mx, 16, 64));
        mx = fmaxf(mx, __shfl_xor(mx, 32, 64));
        float mnew = fmaxf(m, mx);
        float alpha = __expf(m - mnew);

        float rsum = 0.f;
        unsigned int pk[4][2];
        #pragma unroll
        for (int nt = 0; nt < 4; ++nt) {
            __bf16 pb[4];
            #pragma unroll
            for (int r = 0; r < 4; ++r) {
                float e = __expf(p[nt][r] - mnew);
                pb[r] = (__bf16)e;
                rsum += (float)pb[r];   // sum bf16-rounded P: normalization cancels
            }
            pk[nt][0] = bf16bits(pb[0]) | (bf16bits(pb[1]) << 16);
            pk[nt][1] = bf16bits(pb[2]) | (bf16bits(pb[3]) << 16);
        }
        rsum += __shfl_xor(rsum, 16, 64);
        rsum += __shfl_xor(rsum, 32, 64);
        lsum = lsum * alpha + rsum;
        m = mnew;

        // P^T -> PlT[w][qrow=ll][key]; key = nt*16 + lg*4 + r (packed dword pairs)
        #pragma unroll
        for (int nt = 0; nt < 4; ++nt) {
            uint2 u2; u2.x = pk[nt][0]; u2.y = pk[nt][1];
            *(uint2*)&PlT[w][ll][nt * 16 + lg * 4] = u2;
        }
        asm volatile("s_waitcnt lgkmcnt(0)" ::: "memory");
        __builtin_amdgcn_sched_barrier(0);

        // rescale O: need alpha for q-rows lg*4+r (held at lane lg*4+r)
        float arow[4];
        #pragma unroll
        for (int r = 0; r < 4; ++r) arow[r] = __shfl(alpha, lg * 4 + r, 64);
        #pragma unroll
        for (int dt = 0; dt < 8; ++dt)
            #pragma unroll
            for (int r = 0; r < 4; ++r) o[dt][r] *= arow[r];

        // PV: O += P @ V
        #pragma unroll
        for (int kc = 0; kc < 2; ++kc) {
            bf16x8 pa = *(const bf16x8*)&PlT[w][ll][kc * 32 + lg * 8];
            #pragma unroll
            for (int dt = 0; dt < 8; ++dt) {
                bf16x8 vb = *(const bf16x8*)&Vl[g][dt * 16 + ll][kc * 32 + lg * 8];
                o[dt] = __builtin_amdgcn_mfma_f32_16x16x32_bf16(pa, vb, o[dt], 0, 0, 0);
            }
        }

        __syncthreads();            // all waves done reading tile `it`
        if (it + 1 < 32) {
            #pragma unroll
            for (int ii = 0; ii < 4; ++ii) *(bf16x8*)&Kl[g][ur[ii]][uc[ii] * 8] = kreg[ii];
            #pragma unroll
            for (int ii = 0; ii < 4; ++ii) *(bf16x8*)&Vl[g][vr[ii]][vc * 8] = vreg[ii];
        }
        __syncthreads();            // staged writes visible
    }

    // ---- split-K merge ----
    if (lg == 0) { m_l[g][rb + ll] = m; l_l[g][rb + ll] = lsum; }
    __syncthreads();

    float a_own[4], inv[4];
    #pragma unroll
    for (int r = 0; r < 4; ++r) {
        int qr = rb + lg * 4 + r;
        float m0 = m_l[0][qr], m1 = m_l[1][qr];
        float l0 = l_l[0][qr], l1 = l_l[1][qr];
        float mst = fmaxf(m0, m1);
        float a0 = __expf(m0 - mst), a1 = __expf(m1 - mst);
        float lst = l0 * a0 + l1 * a1;
        a_own[r] = (g == 0) ? a0 : a1;
        inv[r] = 1.f / lst;
    }
    if (g == 1) {
        #pragma unroll
        for (int dt = 0; dt < 8; ++dt)
            #pragma unroll
            for (int r = 0; r < 4; ++r)
                Obuf[rb + lg * 4 + r][dt * 16 + ll] = o[dt][r] * a_own[r];
    }
    __syncthreads();
    if (g == 0) {
        float* ob = out + (long)(b * 4096 + qt * 64) * 128;
        #pragma unroll
        for (int r = 0; r < 4; ++r) {
            int qr = rb + lg * 4 + r;
            #pragma unroll
            for (int dt = 0; dt < 8; ++dt)
                ob[qr * 128 + dt * 16 + ll] =
                    (o[dt][r] * a_own[r] + Obuf[qr][dt * 16 + ll]) * inv[r];
        }
    }
}

extern "C" void kernel_launch(void* const* d_in, const int* in_sizes, int n_in,
                              void* d_out, int out_size, void* d_ws, size_t ws_size,
                              hipStream_t stream) {
    (void)in_sizes; (void)n_in; (void)out_size; (void)ws_size;
    const float* x  = (const float*)d_in[0];
    const float* Wq = (const float*)d_in[1];
    const float* bq = (const float*)d_in[2];
    const float* Wk = (const float*)d_in[3];
    const float* bk = (const float*)d_in[4];
    const float* Wv = (const float*)d_in[5];
    const float* bv = (const float*)d_in[6];
    float* out = (float*)d_out;

    __bf16* Q  = (__bf16*)d_ws;                  // 4 MB
    __bf16* K  = Q + NB * SEQ * DIM;             // 4 MB
    __bf16* Vt = K + NB * SEQ * DIM;             // 4 MB
    __bf16* Wh = Vt + NB * SEQ * DIM;            // 96 KB
    __bf16* Wl = Wh + 3 * DIM * DIM;             // 96 KB

    wconv<<<48, 256, 0, stream>>>(Wq, Wk, Wv, Wh, Wl);
    dim3 g1(256, 3), b1(256);
    qkv_proj<<<g1, b1, 0, stream>>>(x, Wh, Wl, bq, bk, bv, Q, K, Vt);
    attn_fwd<<<256, 512, 0, stream>>>(Q, K, Vt, out);
}